// Round 1
// baseline (279.142 us; speedup 1.0000x reference)
//
#include <hip/hip_runtime.h>
#include <math.h>

#define Hh 193
#define Wt 193
#define Mm 64
#define NH 192
#define NW 192
#define NB (NH*NW)          // 36864
#define TROW 4096           // 64*64 table row

// ---------------- kernel 1: cos tables ----------------
// C[k][t]  = cos(2*pi*k/(t+2)),  t = i*64+j in [0,4096)
// CP[k][t] = C[k][t] * P[t]
__global__ void k_tables(const float* __restrict__ P,
                         float* __restrict__ C,
                         float* __restrict__ CP) {
    int idx = blockIdx.x * 256 + threadIdx.x;   // 192*4096 = 786432 threads
    int k = idx >> 12;
    int t = idx & (TROW - 1);
    float p = (float)(t + 2);
    float ang = 6.28318530717958647692f * (float)k / p;
    float c = cosf(ang);
    C[idx] = c;
    CP[idx] = c * P[t];
}

// ---------------- kernel 2: x = win_avg(grid) @ M^T ----------------
// one 64-thread block per b = k1*NW + k2
__global__ void k_x(const float* __restrict__ grid,
                    const float* __restrict__ Mw,
                    float* __restrict__ x) {
    int b = blockIdx.x;
    int k1 = b / NW, k2 = b - k1 * NW;
    int i = threadIdx.x;
    __shared__ float xw[Mm];
    const float* g0 = grid + ((size_t)k1 * Wt + k2) * Mm;
    float s = g0[i] + g0[Mm + i] + g0[(size_t)Wt * Mm + i] + g0[(size_t)Wt * Mm + Mm + i];
    xw[i] = s * 0.25f;
    __syncthreads();
    const float4* mr4 = (const float4*)(Mw + (size_t)i * Mm);
    const float4* xw4 = (const float4*)xw;
    float acc = 0.f;
    #pragma unroll
    for (int c4 = 0; c4 < 16; ++c4) {
        float4 xv = xw4[c4];
        float4 mv = mr4[c4];
        acc += xv.x * mv.x + xv.y * mv.y + xv.z * mv.z + xv.w * mv.w;
    }
    x[(size_t)b * Mm + i] = acc;
}

// ---------------- kernel 3: Nk[b,i] = sum_j x[b,j]*CP[k1,i*64+j]*C[k2,i*64+j] ----------------
// block = 256 threads (4 waves); block handles (k1, group of 16 k2).
// wave w processes k2 = g*16 + w*4 + t, t=0..3; lane = output i.
// CP row segment (64 floats) held in registers, reused across 4 k2.
__global__ __launch_bounds__(256) void k_main(const float* __restrict__ x,
                                              const float* __restrict__ C,
                                              const float* __restrict__ CP,
                                              float* __restrict__ out) {
    int bx = blockIdx.x;            // 0..(192*12-1)
    int k1 = bx % NH;               // fast index -> consecutive blocks share k2-group (hot C rows)
    int g  = bx / NH;               // k2 group of 16
    int w  = __builtin_amdgcn_readfirstlane((int)(threadIdx.x >> 6));
    int lane = threadIdx.x & 63;    // i

    const float4* cp4 = (const float4*)(CP + ((size_t)k1 << 12) + (lane << 6));
    float4 cp[16];
    #pragma unroll
    for (int q = 0; q < 16; ++q) cp[q] = cp4[q];

    #pragma unroll
    for (int t = 0; t < 4; ++t) {
        int k2 = g * 16 + w * 4 + t;                 // wave-uniform
        const float4* xb4 = (const float4*)(x + (((size_t)k1 * NW + k2) << 6)); // uniform addr
        const float4* c4  = (const float4*)(C + ((size_t)k2 << 12) + (lane << 6));
        float acc = 0.f;
        #pragma unroll
        for (int q = 0; q < 16; ++q) {
            float4 xv = xb4[q];
            float4 cv = c4[q];
            float4 cpq = cp[q];
            acc += (xv.x * cpq.x) * cv.x;
            acc += (xv.y * cpq.y) * cv.y;
            acc += (xv.z * cpq.z) * cv.z;
            acc += (xv.w * cpq.w) * cv.w;
        }
        out[(((size_t)k1 * NW + k2) << 6) + lane] = acc;
    }
}

extern "C" void kernel_launch(void* const* d_in, const int* in_sizes, int n_in,
                              void* d_out, int out_size, void* d_ws, size_t ws_size,
                              hipStream_t stream) {
    const float* grid = (const float*)d_in[0];   // [193,193,64]
    const float* Mw   = (const float*)d_in[1];   // [64,64]
    const float* P    = (const float*)d_in[2];   // [64,64]
    float* out = (float*)d_out;                  // [36864,64]

    // workspace layout (floats): C [192*4096] | CP [192*4096] | x [36864*64]
    float* C  = (float*)d_ws;
    float* CP = C + (size_t)NH * TROW;
    float* x  = CP + (size_t)NH * TROW;

    k_tables<<<(NH * TROW) / 256, 256, 0, stream>>>(P, C, CP);
    k_x<<<NB, 64, 0, stream>>>(grid, Mw, x);
    k_main<<<NH * (NW / 16), 256, 0, stream>>>(x, C, CP, out);
}

// Round 2
// 131.264 us; speedup vs baseline: 2.1266x; 2.1266x over previous
//
#include <hip/hip_runtime.h>
#include <math.h>

#define Hh 193
#define Wt 193
#define NH 192
#define NW 192
#define NB (NH*NW)          // 36864
#define TROW 4096           // 64*64 table row (words)
#define SEGW 68             // 64 words + 4 pad per i-segment (bank swizzle)
#define ROWW (64*SEGW)      // 4352 words = 17408 B per swizzled row
#define T1 8                // k1 per block (one per wave)
#define T2 8                // k2 per block (staged loop)

// ---------------- kernel 1: cos tables ----------------
// C[k][t]  = cos(2*pi*k/(t+2)),  t = i*64+j in [0,4096)
// CP[k][t] = C[k][t] * P[t]
__global__ void k_tables(const float* __restrict__ P,
                         float* __restrict__ C,
                         float* __restrict__ CP) {
    int idx = blockIdx.x * 256 + threadIdx.x;   // 192*4096 threads
    int k = idx >> 12;
    int t = idx & (TROW - 1);
    float p = (float)(t + 2);
    float ang = 6.28318530717958647692f * (float)k / p;
    float c = cosf(ang);
    C[idx] = c;
    CP[idx] = c * P[t];
}

// ---------------- kernel 2: x = win_avg(grid) @ M^T ----------------
// block = 256 threads (4 waves); handles 16 consecutive k2 at one k1.
// M staged into swizzled LDS once, hoisted to registers, reused for 4 b/wave.
__global__ __launch_bounds__(256) void k_x(const float* __restrict__ grid,
                                           const float* __restrict__ Mw,
                                           float* __restrict__ x) {
    __shared__ float Ms[ROWW];       // swizzled 64x64 M
    __shared__ float win[16][64];    // window averages for the 16 b's
    int bx = blockIdx.x;             // 192 * 12
    int k2g = bx % (NW / 16);        // 0..11
    int k1  = bx / (NW / 16);        // 0..191
    int t = threadIdx.x;

    // stage M: coalesced global read, swizzled LDS write
    #pragma unroll
    for (int r = 0; r < 4; ++r) {
        int c = r * 256 + t;                       // chunk = i*16+q
        float4 v = ((const float4*)Mw)[c];
        *(float4*)&Ms[(c >> 4) * SEGW + 4 * (c & 15)] = v;
    }

    // window sums: thread handles (bl, c), coalesced in c
    int cc = t & 63;
    int w  = t >> 6;
    const float* gbase = grid + ((size_t)k1 * Wt + (size_t)k2g * 16) * 64;
    #pragma unroll
    for (int r = 0; r < 4; ++r) {
        int bl = w * 4 + r;                        // 0..15
        const float* g0 = gbase + (size_t)bl * 64;
        float s = g0[cc] + g0[64 + cc] + g0[Wt * 64 + cc] + g0[Wt * 64 + 64 + cc];
        win[bl][cc] = s * 0.25f;
    }
    __syncthreads();

    // hoist M row (for lane's i) into registers
    int i = cc;
    float4 mr[16];
    #pragma unroll
    for (int q = 0; q < 16; ++q)
        mr[q] = *(const float4*)&Ms[i * SEGW + 4 * q];

    // each wave computes 4 b's: x[b,i] = sum_c win[bl][c] * M[i][c]
    #pragma unroll
    for (int r = 0; r < 4; ++r) {
        int bl = w * 4 + r;
        float acc = 0.f;
        #pragma unroll
        for (int q = 0; q < 16; ++q) {
            float4 wv = *(const float4*)&win[bl][4 * q];   // uniform -> broadcast
            float4 mv = mr[q];
            acc += mv.x * wv.x + mv.y * wv.y + mv.z * wv.z + mv.w * wv.w;
        }
        x[(((size_t)k1 * NW) + (k2g * 16 + bl)) * 64 + i] = acc;
    }
}

// ---------------- kernel 3: Nk[b,i] = sum_j x[b,j]*CP[k1,i*64+j]*C[k2,i*64+j] ----------------
// block = 512 threads (8 waves). wave w -> k1 = k1g*8+w. k2-loop of 8, C row
// double-buffer staged in swizzled LDS. CP[k1] segment register-resident.
__global__ __launch_bounds__(512) void k_main(const float* __restrict__ x,
                                              const float* __restrict__ C,
                                              const float* __restrict__ CP,
                                              float* __restrict__ out) {
    __shared__ float buf[2][ROWW];   // 2 * 17408 B
    int bx = blockIdx.x;             // 24 * 24 = 576
    int k1g = bx % (NH / T1);        // fast index: consecutive blocks share k2 rows
    int k2g = bx / (NH / T1);
    int t = threadIdx.x;
    int w = t >> 6;                  // 0..7
    int lane = t & 63;               // output i
    int k1 = k1g * T1 + w;
    int k2base = k2g * T2;

    // CP[k1] segment for lane's i -> registers (one-time, L1/L2 cached)
    const float4* cp4 = (const float4*)(CP + ((size_t)k1 << 12) + (lane << 6));
    float4 cp[16];
    #pragma unroll
    for (int q = 0; q < 16; ++q) cp[q] = cp4[q];

    // stage first C row into buf[0]: coalesced read, swizzled write
    {
        const float4* src = (const float4*)(C + ((size_t)k2base << 12));
        #pragma unroll
        for (int r = 0; r < 2; ++r) {
            int c = r * 512 + t;
            float4 v = src[c];
            *(float4*)&buf[0][(c >> 4) * SEGW + 4 * (c & 15)] = v;
        }
    }
    __syncthreads();

    for (int kk = 0; kk < T2; ++kk) {
        // prefetch next row into the other buffer
        if (kk + 1 < T2) {
            const float4* src = (const float4*)(C + ((size_t)(k2base + kk + 1) << 12));
            #pragma unroll
            for (int r = 0; r < 2; ++r) {
                int c = r * 512 + t;
                float4 v = src[c];
                *(float4*)&buf[(kk + 1) & 1][(c >> 4) * SEGW + 4 * (c & 15)] = v;
            }
        }
        const float* bb = buf[kk & 1];
        int k2 = k2base + kk;
        const float4* xb4 = (const float4*)(x + (((size_t)k1 * NW + k2) << 6)); // uniform
        float acc = 0.f;
        #pragma unroll
        for (int q = 0; q < 16; ++q) {
            float4 cv = *(const float4*)&bb[lane * SEGW + 4 * q];  // conflict-optimal
            float4 xv = xb4[q];
            float4 cpq = cp[q];
            acc += (xv.x * cpq.x) * cv.x + (xv.y * cpq.y) * cv.y
                 + (xv.z * cpq.z) * cv.z + (xv.w * cpq.w) * cv.w;
        }
        out[(((size_t)k1 * NW + k2) << 6) + lane] = acc;
        __syncthreads();
    }
}

extern "C" void kernel_launch(void* const* d_in, const int* in_sizes, int n_in,
                              void* d_out, int out_size, void* d_ws, size_t ws_size,
                              hipStream_t stream) {
    const float* grid = (const float*)d_in[0];   // [193,193,64]
    const float* Mw   = (const float*)d_in[1];   // [64,64]
    const float* P    = (const float*)d_in[2];   // [64,64]
    float* out = (float*)d_out;                  // [36864,64]

    // workspace layout (floats): C [192*4096] | CP [192*4096] | x [36864*64]
    float* C  = (float*)d_ws;
    float* CP = C + (size_t)NH * TROW;
    float* x  = CP + (size_t)NH * TROW;

    k_tables<<<(NH * TROW) / 256, 256, 0, stream>>>(P, C, CP);
    k_x<<<NH * (NW / 16), 256, 0, stream>>>(grid, Mw, x);
    k_main<<<(NH / T1) * (NW / T2), 512, 0, stream>>>(x, C, CP, out);
}

// Round 3
// 111.850 us; speedup vs baseline: 2.4957x; 1.1736x over previous
//
#include <hip/hip_runtime.h>
#include <math.h>

#define NH 192
#define NW 192
#define Wt 193
#define TG 24              // tiles per dim (192/8)
#define NTILE (TG*TG)      // 576
#define TILE_SZ 4096       // 64 j * 64 p

// ---------------- kernel 1: transposed cos tables ----------------
// Cz [j][kg][i][r] = cos(2*pi*k/(i*64+j+2)),  k = kg*4+r,  j,i in [0,64), kg in [0,48)
// CPz[j][kg][i][r] = Cz * P[i][j]
__global__ void k_tables(const float* __restrict__ P,
                         float* __restrict__ Cz,
                         float* __restrict__ CPz) {
    int idx = blockIdx.x * 256 + threadIdx.x;   // 64*48*64*4 = 786432
    int r  = idx & 3;
    int i  = (idx >> 2) & 63;
    int kg = (idx >> 8) % 48;
    int j  = idx / 12288;                       // 48*256
    int k  = kg * 4 + r;
    int t  = i * 64 + j;
    float ang = 6.28318530717958647692f * (float)k / (float)(t + 2);
    float c = cosf(ang);
    Cz[idx]  = c;
    CPz[idx] = c * P[t];
}

// ---------------- kernel 2: xt[tile][j][p] = (win_avg @ M^T) tiled ----------------
// block = 256 thr handles one 8x8 (k1,k2) tile: 64 b's (p = l1*8+l2), all 64 j.
__global__ __launch_bounds__(256) void k_x(const float* __restrict__ grid,
                                           const float* __restrict__ Mw,
                                           float* __restrict__ xt) {
    __shared__ float Ms[64 * 64];    // M[j][c] plain (uniform reads)
    __shared__ float win[64 * 68];   // win[p][c], stride 68 (bank swizzle)
    int bx = blockIdx.x;             // 576
    int k1g = bx % TG, k2g = bx / TG;
    int t = threadIdx.x;

    // stage M (coalesced)
    #pragma unroll
    for (int r = 0; r < 4; ++r) {
        int e = r * 256 + t;
        ((float4*)Ms)[e] = ((const float4*)Mw)[e];
    }

    // window averages: lane = channel c, 16 p's per thread-group
    {
        int c = t & 63, pq = t >> 6;
        const float* gb = grid + ((size_t)(k1g * 8) * Wt + k2g * 8) * 64;
        #pragma unroll
        for (int r = 0; r < 16; ++r) {
            int p = pq * 16 + r;
            int l1 = p >> 3, l2 = p & 7;
            const float* g0 = gb + ((size_t)l1 * Wt + l2) * 64;
            float s = g0[c] + g0[64 + c] + g0[Wt * 64 + c] + g0[Wt * 64 + 64 + c];
            win[p * 68 + c] = 0.25f * s;
        }
    }
    __syncthreads();

    // x[p][j] = sum_c win[p][c] * M[j][c]; lane = p -> coalesced stores
    int p = t & 63, jq = t >> 6;
    float4 wv[16];
    #pragma unroll
    for (int q = 0; q < 16; ++q) wv[q] = *(const float4*)&win[p * 68 + 4 * q];

    float* xb = xt + (size_t)(k1g * TG + k2g) * TILE_SZ;
    #pragma unroll
    for (int r = 0; r < 16; ++r) {
        int j = jq * 16 + r;
        float acc = 0.f;
        #pragma unroll
        for (int q = 0; q < 16; ++q) {
            float4 mv = *(const float4*)&Ms[j * 64 + 4 * q];   // uniform broadcast
            acc += wv[q].x * mv.x + wv[q].y * mv.y + wv[q].z * mv.z + wv[q].w * mv.w;
        }
        xb[(size_t)j * 64 + p] = acc;    // coalesced
    }
}

// ---------------- kernel 3: Nk ----------------
// block = 256 thr = 4 waves; tile = 8x8 pairs; lane = i; wave = j-quarter.
// acc[8][8] per lane; per j: c1[8]+c2[8] coalesced float4 loads, x uniform loads.
__global__ __launch_bounds__(256, 3) void k_main(const float* __restrict__ xt,
                                                 const float* __restrict__ Cz,
                                                 const float* __restrict__ CPz,
                                                 float* __restrict__ out) {
    __shared__ float red[3 * 4096];  // 48 KB: waves 1..3 partials
    int bx = blockIdx.x;             // 576
    int k1g = bx % TG, k2g = bx / TG;  // consecutive blocks share k2g's c2 slice
    int t = threadIdx.x;
    int lane = t & 63;               // i
    int w = t >> 6;                  // j-quarter

    const float4* c1p = (const float4*)CPz;
    const float4* c2p = (const float4*)Cz;
    const float4* xp  = (const float4*)(xt + (size_t)(k1g * TG + k2g) * TILE_SZ);
    int kg1 = k1g * 2, kg2 = k2g * 2;

    float acc[8][8];
    #pragma unroll
    for (int a = 0; a < 8; ++a)
        #pragma unroll
        for (int b = 0; b < 8; ++b) acc[a][b] = 0.f;

    for (int jj = 0; jj < 16; ++jj) {
        int j = w * 16 + jj;
        float4 a0 = c1p[(j * 48 + kg1) * 64 + lane];
        float4 a1 = c1p[(j * 48 + kg1 + 1) * 64 + lane];
        float4 b0 = c2p[(j * 48 + kg2) * 64 + lane];
        float4 b1 = c2p[(j * 48 + kg2 + 1) * 64 + lane];
        float c1f[8] = {a0.x, a0.y, a0.z, a0.w, a1.x, a1.y, a1.z, a1.w};
        float c2f[8] = {b0.x, b0.y, b0.z, b0.w, b1.x, b1.y, b1.z, b1.w};
        const float4* xj = xp + j * 16;
        #pragma unroll
        for (int q = 0; q < 16; ++q) {
            float4 xv = xj[q];                      // uniform
            int p0 = q * 4;
            acc[(p0 + 0) >> 3][(p0 + 0) & 7] += xv.x * (c1f[(p0 + 0) >> 3] * c2f[(p0 + 0) & 7]);
            acc[(p0 + 1) >> 3][(p0 + 1) & 7] += xv.y * (c1f[(p0 + 1) >> 3] * c2f[(p0 + 1) & 7]);
            acc[(p0 + 2) >> 3][(p0 + 2) & 7] += xv.z * (c1f[(p0 + 2) >> 3] * c2f[(p0 + 2) & 7]);
            acc[(p0 + 3) >> 3][(p0 + 3) & 7] += xv.w * (c1f[(p0 + 3) >> 3] * c2f[(p0 + 3) & 7]);
        }
    }

    // cross-wave reduction: waves 1..3 dump, wave 0 sums + stores
    if (w > 0) {
        float* rd = red + (w - 1) * 4096;
        #pragma unroll
        for (int p = 0; p < 64; ++p) rd[p * 64 + lane] = acc[p >> 3][p & 7];
    }
    __syncthreads();
    if (w == 0) {
        size_t ob = ((size_t)(k1g * 8) * NW + k2g * 8) * 64;
        #pragma unroll
        for (int p = 0; p < 64; ++p) {
            float s = acc[p >> 3][p & 7]
                    + red[p * 64 + lane]
                    + red[4096 + p * 64 + lane]
                    + red[8192 + p * 64 + lane];
            out[ob + ((size_t)(p >> 3) * NW + (p & 7)) * 64 + lane] = s;
        }
    }
}

extern "C" void kernel_launch(void* const* d_in, const int* in_sizes, int n_in,
                              void* d_out, int out_size, void* d_ws, size_t ws_size,
                              hipStream_t stream) {
    const float* grid = (const float*)d_in[0];   // [193,193,64]
    const float* Mw   = (const float*)d_in[1];   // [64,64]
    const float* P    = (const float*)d_in[2];   // [64,64]
    float* out = (float*)d_out;                  // [36864,64]

    // ws layout (floats): Cz [786432] | CPz [786432] | xt [576*4096]
    float* Cz  = (float*)d_ws;
    float* CPz = Cz + 786432;
    float* xt  = CPz + 786432;

    k_tables<<<3072, 256, 0, stream>>>(P, Cz, CPz);
    k_x<<<NTILE, 256, 0, stream>>>(grid, Mw, xt);
    k_main<<<NTILE, 256, 0, stream>>>(xt, Cz, CPz, out);
}

// Round 4
// 106.146 us; speedup vs baseline: 2.6298x; 1.0537x over previous
//
#include <hip/hip_runtime.h>
#include <math.h>

#define NH 192
#define NW 192
#define Wt 193
#define TG 24              // tiles per dim (192/8)
#define NTILE (TG*TG)      // 576
#define TILE_SZ 4096       // 64 j * 64 p
#define TWO_PI 6.28318530717958647692f
#define TBLK 3072          // table-builder blocks in fused prep kernel

// ---------------- fused prep: tables + x ----------------
// blocks [0,TBLK): build both cos tables (coalesced stores)
//   Cz [j][kg][i][r] = cos(2*pi*(kg*4+r)/(i*64+j+2))          (k2 side, float4-packed)
//   CP1[j][k][i]     = cos(2*pi*k/(i*64+j+2)) * P[i][j]       (k1 side, row-packed)
// blocks [TBLK, TBLK+576): xt[tile][j][p] = (win_avg @ M^T), p = l1*8+l2 local
__global__ __launch_bounds__(256) void k_prep(const float* __restrict__ grid,
                                              const float* __restrict__ Mw,
                                              const float* __restrict__ P,
                                              float* __restrict__ Cz,
                                              float* __restrict__ CP1,
                                              float* __restrict__ xt) {
    __shared__ float Ms[64 * 64];    // M[j][c]
    __shared__ float win[64 * 68];   // win[p][c], stride 68
    int bx = blockIdx.x;
    int t = threadIdx.x;

    if (bx < TBLK) {
        int idx = bx * 256 + t;                 // 0..786431
        // Cz entry
        int r  = idx & 3;
        int i  = (idx >> 2) & 63;
        int kg = (idx >> 8) % 48;
        int j  = idx / 12288;
        int k  = kg * 4 + r;
        Cz[idx] = cosf(TWO_PI * (float)k / (float)(i * 64 + j + 2));
        // CP1 entry (different mapping, same flat size)
        int i2 = idx & 63;
        int k2 = (idx >> 6) % 192;
        int j2 = idx / 12288;
        int t2 = i2 * 64 + j2;
        CP1[idx] = cosf(TWO_PI * (float)k2 / (float)(t2 + 2)) * P[t2];
        return;
    }

    int bb = bx - TBLK;                         // 0..575
    int k1g = bb % TG, k2g = bb / TG;

    // stage M (coalesced)
    #pragma unroll
    for (int r = 0; r < 4; ++r) {
        int e = r * 256 + t;
        ((float4*)Ms)[e] = ((const float4*)Mw)[e];
    }

    // window averages: lane = channel c
    {
        int c = t & 63, pq = t >> 6;
        const float* gb = grid + ((size_t)(k1g * 8) * Wt + k2g * 8) * 64;
        #pragma unroll
        for (int r = 0; r < 16; ++r) {
            int p = pq * 16 + r;
            int l1 = p >> 3, l2 = p & 7;
            const float* g0 = gb + ((size_t)l1 * Wt + l2) * 64;
            float s = g0[c] + g0[64 + c] + g0[Wt * 64 + c] + g0[Wt * 64 + 64 + c];
            win[p * 68 + c] = 0.25f * s;
        }
    }
    __syncthreads();

    // x[p][j] = sum_c win[p][c] * M[j][c]; lane = p -> coalesced stores
    int p = t & 63, jq = t >> 6;
    float4 wv[16];
    #pragma unroll
    for (int q = 0; q < 16; ++q) wv[q] = *(const float4*)&win[p * 68 + 4 * q];

    float* xb = xt + (size_t)(k1g * TG + k2g) * TILE_SZ;
    #pragma unroll
    for (int r = 0; r < 16; ++r) {
        int j = jq * 16 + r;
        float acc = 0.f;
        #pragma unroll
        for (int q = 0; q < 16; ++q) {
            float4 mv = *(const float4*)&Ms[j * 64 + 4 * q];   // uniform broadcast
            acc += wv[q].x * mv.x + wv[q].y * mv.y + wv[q].z * mv.z + wv[q].w * mv.w;
        }
        xb[(size_t)j * 64 + p] = acc;    // coalesced
    }
}

// ---------------- k_main: Nk[b,i] ----------------
// 512 thr = 8 waves; tile = 8x8 pairs; wave w owns k1-row w (8 pairs), all 64 j.
// lane = i. No LDS, no barriers, acc[8] in VGPRs.
__global__ __launch_bounds__(512) void k_main(const float* __restrict__ xt,
                                              const float* __restrict__ Cz,
                                              const float* __restrict__ CP1,
                                              float* __restrict__ out) {
    int bx = blockIdx.x;             // 576; consecutive blocks share k2g (c2 slice hot)
    int k1g = bx % TG, k2g = bx / TG;
    int t = threadIdx.x;
    int lane = t & 63;               // i
    int w = __builtin_amdgcn_readfirstlane(t >> 6);   // 0..7 = local l1
    int k1 = k1g * 8 + w;

    const float*  c1p = CP1 + (size_t)k1 * 64 + lane;                    // += 12288/j
    const float4* c2p = (const float4*)Cz + (size_t)(k2g * 2) * 64 + lane; // += 3072/j
    const float*  xb  = xt + (size_t)(k1g * TG + k2g) * TILE_SZ + w * 8; // += 64/j (uniform)

    float acc[8];
    #pragma unroll
    for (int l2 = 0; l2 < 8; ++l2) acc[l2] = 0.f;

    #pragma unroll 4
    for (int j = 0; j < 64; ++j) {
        float  c1 = *c1p;                     // coalesced dword
        float4 v0 = c2p[0];                   // coalesced float4
        float4 v1 = c2p[64];
        float4 x0 = ((const float4*)xb)[0];   // uniform addr -> scalar-promotable
        float4 x1 = ((const float4*)xb)[1];
        float c2f[8] = {v0.x, v0.y, v0.z, v0.w, v1.x, v1.y, v1.z, v1.w};
        float xs[8]  = {x0.x, x0.y, x0.z, x0.w, x1.x, x1.y, x1.z, x1.w};
        #pragma unroll
        for (int l2 = 0; l2 < 8; ++l2)
            acc[l2] += xs[l2] * (c1 * c2f[l2]);
        c1p += 12288;          // 192*64
        c2p += 3072;           // 48*64 float4s
        xb  += 64;
    }

    size_t ob = ((size_t)k1 * NW + k2g * 8) * 64 + lane;
    #pragma unroll
    for (int l2 = 0; l2 < 8; ++l2)
        out[ob + (size_t)l2 * 64] = acc[l2];  // coalesced dword stores
}

extern "C" void kernel_launch(void* const* d_in, const int* in_sizes, int n_in,
                              void* d_out, int out_size, void* d_ws, size_t ws_size,
                              hipStream_t stream) {
    const float* grid = (const float*)d_in[0];   // [193,193,64]
    const float* Mw   = (const float*)d_in[1];   // [64,64]
    const float* P    = (const float*)d_in[2];   // [64,64]
    float* out = (float*)d_out;                  // [36864,64]

    // ws layout (floats): Cz [786432] | CP1 [786432] | xt [576*4096]
    float* Cz  = (float*)d_ws;
    float* CP1 = Cz + 786432;
    float* xt  = CP1 + 786432;

    k_prep<<<TBLK + NTILE, 256, 0, stream>>>(grid, Mw, P, Cz, CP1, xt);
    k_main<<<NTILE, 512, 0, stream>>>(xt, Cz, CP1, out);
}

// Round 5
// 94.996 us; speedup vs baseline: 2.9385x; 1.1174x over previous
//
#include <hip/hip_runtime.h>
#include <math.h>

#define NH 192
#define NW 192
#define Wt 193
#define TG 24              // tiles per dim (192/8)
#define NTILE (TG*TG)      // 576
#define TILE_SZ 4096       // 64 j * 64 p
#define TBLK 3072          // table-builder blocks in fused prep kernel

// cos(2*pi*num/den) via HW cos (input in revolutions)
__device__ __forceinline__ float cos_rev(float num, float den) {
    float rev = num * __builtin_amdgcn_rcpf(den);
    rev = __builtin_amdgcn_fractf(rev);
    return __builtin_amdgcn_cosf(rev);
}

// ---------------- fused prep: tables + x ----------------
// blocks [0,TBLK): build both cos tables (coalesced stores)
//   Cz [j][kg][i][r] = cos(2*pi*(kg*4+r)/(i*64+j+2))          (k2 side, float4-packed)
//   CP1[j][k][i]     = cos(2*pi*k/(i*64+j+2)) * P[i][j]       (k1 side, row-packed)
// blocks [TBLK, TBLK+576): xt[tile][j][p] = (win_avg @ M^T), p = l1*8+l2 local
__global__ __launch_bounds__(256) void k_prep(const float* __restrict__ grid,
                                              const float* __restrict__ Mw,
                                              const float* __restrict__ P,
                                              float* __restrict__ Cz,
                                              float* __restrict__ CP1,
                                              float* __restrict__ xt) {
    __shared__ float Ms[64 * 64];    // M[j][c]
    __shared__ float win[64 * 68];   // win[p][c], stride 68
    int bx = blockIdx.x;
    int t = threadIdx.x;

    if (bx < TBLK) {
        int idx = bx * 256 + t;                 // 0..786431
        // Cz entry
        int r  = idx & 3;
        int i  = (idx >> 2) & 63;
        int kg = (idx >> 8) % 48;
        int j  = idx / 12288;
        int k  = kg * 4 + r;
        Cz[idx] = cos_rev((float)k, (float)(i * 64 + j + 2));
        // CP1 entry (different mapping, same flat size)
        int i2 = idx & 63;
        int k2 = (idx >> 6) % 192;
        int j2 = idx / 12288;
        int t2 = i2 * 64 + j2;
        CP1[idx] = cos_rev((float)k2, (float)(t2 + 2)) * P[t2];
        return;
    }

    int bb = bx - TBLK;                         // 0..575
    int k1g = bb % TG, k2g = bb / TG;

    // stage M (coalesced)
    #pragma unroll
    for (int r = 0; r < 4; ++r) {
        int e = r * 256 + t;
        ((float4*)Ms)[e] = ((const float4*)Mw)[e];
    }

    // window averages: lane = channel c
    {
        int c = t & 63, pq = t >> 6;
        const float* gb = grid + ((size_t)(k1g * 8) * Wt + k2g * 8) * 64;
        #pragma unroll
        for (int r = 0; r < 16; ++r) {
            int p = pq * 16 + r;
            int l1 = p >> 3, l2 = p & 7;
            const float* g0 = gb + ((size_t)l1 * Wt + l2) * 64;
            float s = g0[c] + g0[64 + c] + g0[Wt * 64 + c] + g0[Wt * 64 + 64 + c];
            win[p * 68 + c] = 0.25f * s;
        }
    }
    __syncthreads();

    // x[p][j] = sum_c win[p][c] * M[j][c]; lane = p -> coalesced stores
    int p = t & 63, jq = t >> 6;
    float4 wv[16];
    #pragma unroll
    for (int q = 0; q < 16; ++q) wv[q] = *(const float4*)&win[p * 68 + 4 * q];

    float* xb = xt + (size_t)(k1g * TG + k2g) * TILE_SZ;
    #pragma unroll
    for (int r = 0; r < 16; ++r) {
        int j = jq * 16 + r;
        float acc = 0.f;
        #pragma unroll
        for (int q = 0; q < 16; ++q) {
            float4 mv = *(const float4*)&Ms[j * 64 + 4 * q];   // uniform broadcast
            acc += wv[q].x * mv.x + wv[q].y * mv.y + wv[q].z * mv.z + wv[q].w * mv.w;
        }
        xb[(size_t)j * 64 + p] = acc;    // coalesced
    }
}

// ---------------- k_main: Nk[b,i] ----------------
// 512 thr = 8 waves; tile = 8x8 pairs; wave w owns k1-row w (8 pairs), all 64 j.
// lane = i. c2 slice staged in LDS per 16-j chunk (each float4 fetched ONCE per
// block); c1 per-wave coalesced global (unique); x wave-uniform scalar loads.
__global__ __launch_bounds__(512) void k_main(const float* __restrict__ xt,
                                              const float* __restrict__ Cz,
                                              const float* __restrict__ CP1,
                                              float* __restrict__ out) {
    __shared__ float4 cs[2048];      // 32 KB: [jj(16)][g(2)][i(64)]
    int bx = blockIdx.x;             // 576; consecutive blocks share k2g (c2 slice hot)
    int k1g = bx % TG, k2g = bx / TG;
    int t = threadIdx.x;
    int lane = t & 63;               // i
    int w = __builtin_amdgcn_readfirstlane(t >> 6);   // 0..7 = local l1
    int k1 = k1g * 8 + w;

    const float*  c1p = CP1 + (size_t)k1 * 64 + lane;                    // +12288/j
    const float*  xb  = xt + (size_t)(k1g * TG + k2g) * TILE_SZ + w * 8; // +64/j (uniform)
    const float4* Cz4 = (const float4*)Cz;
    int kgb = k2g * 2;

    float acc[8];
    #pragma unroll
    for (int l2 = 0; l2 < 8; ++l2) acc[l2] = 0.f;

    for (int jc = 0; jc < 4; ++jc) {
        __syncthreads();             // previous chunk fully consumed
        #pragma unroll
        for (int r = 0; r < 4; ++r) {
            int e = r * 512 + t;     // [0,2048): jj = e>>7, g = (e>>6)&1, i = e&63
            int jj = e >> 7;
            int g  = (e >> 6) & 1;
            int i  = e & 63;
            cs[e] = Cz4[(size_t)((jc * 16 + jj) * 48 + kgb + g) * 64 + i];  // coalesced
        }
        __syncthreads();

        #pragma unroll 4
        for (int jj = 0; jj < 16; ++jj) {
            int j = jc * 16 + jj;
            float  c1 = c1p[(size_t)j * 12288];          // coalesced dword (L2)
            float4 v0 = cs[jj * 128 + lane];             // ds_read_b128, conflict-free
            float4 v1 = cs[jj * 128 + 64 + lane];
            const float4* xj = (const float4*)(xb + (size_t)j * 64);  // uniform -> s_load
            float4 x0 = xj[0];
            float4 x1 = xj[1];
            float c2f[8] = {v0.x, v0.y, v0.z, v0.w, v1.x, v1.y, v1.z, v1.w};
            float xs[8]  = {x0.x, x0.y, x0.z, x0.w, x1.x, x1.y, x1.z, x1.w};
            #pragma unroll
            for (int l2 = 0; l2 < 8; ++l2)
                acc[l2] += xs[l2] * (c1 * c2f[l2]);
        }
    }

    size_t ob = ((size_t)k1 * NW + k2g * 8) * 64 + lane;
    #pragma unroll
    for (int l2 = 0; l2 < 8; ++l2)
        out[ob + (size_t)l2 * 64] = acc[l2];  // coalesced dword stores
}

extern "C" void kernel_launch(void* const* d_in, const int* in_sizes, int n_in,
                              void* d_out, int out_size, void* d_ws, size_t ws_size,
                              hipStream_t stream) {
    const float* grid = (const float*)d_in[0];   // [193,193,64]
    const float* Mw   = (const float*)d_in[1];   // [64,64]
    const float* P    = (const float*)d_in[2];   // [64,64]
    float* out = (float*)d_out;                  // [36864,64]

    // ws layout (floats): Cz [786432] | CP1 [786432] | xt [576*4096]
    float* Cz  = (float*)d_ws;
    float* CP1 = Cz + 786432;
    float* xt  = CP1 + 786432;

    k_prep<<<TBLK + NTILE, 256, 0, stream>>>(grid, Mw, P, Cz, CP1, xt);
    k_main<<<NTILE, 512, 0, stream>>>(xt, Cz, CP1, out);
}